// Round 1
// baseline (182.561 us; speedup 1.0000x reference)
//
#include <hip/hip_runtime.h>
#include <stdint.h>

#define GLOBAL_AS __attribute__((address_space(1)))
#define LDS_AS __attribute__((address_space(3)))

typedef _Float16 half_t;
typedef _Float16 f16x8 __attribute__((ext_vector_type(8)));
typedef float f32x4 __attribute__((ext_vector_type(4)));

static constexpr int BATCH = 8;
static constexpr int CH = 256;
static constexpr int N = 2304;     // 48*48
static constexpr int KTOT = 4096;  // 2 * BATCH * CH (G1 and G2 fused along K)
static constexpr int MW = 72;      // mask words per row (2304/32)
static constexpr int MWORDS = 165888;  // 2304*72
static constexpr int LROW = 258;   // LDS transpose row stride in halfs (odd word count)
static constexpr float EPS = 1e-8f;
static constexpr float THR = 31.5f;
static constexpr int NBLK = 243;   // 81 output tiles x 3 K-slices (single round, 1 blk/CU)

// ws layout (nothing needs pre-zeroing; every slot written unconditionally):
//   s_part  = ws         : float [243]  per-gemm-block masked-sum partials
//   c_part  = ws + 8192  : uint  [864]  per-mask-block popcount partials
//   At = ws + 16384            : half [2304][4096] rows=n, k-contig ([yhat; zhat])
//   Bt = At + 18874368 B       : half [2304][4096] rows=m, k-contig ([zphat; yphat])
//   maskw = Bt + 18874368 B    : uint32 [2304][72] bitmask of (dist < THR)

// ------------- 1. prep: fused norm+pack (z<4) and mask build (z>=4) -------------
__global__ __launch_bounds__(256) void prep_kernel(
    const float* __restrict__ y, const float* __restrict__ yp,
    const float* __restrict__ z, const float* __restrict__ zp,
    const float* __restrict__ dist,
    half_t* __restrict__ At, half_t* __restrict__ Bt,
    uint32_t* __restrict__ maskw, unsigned int* __restrict__ c_part) {
  const int t = threadIdx.x;
  const int bz = blockIdx.z;

  if (bz >= 4) {
    // ---- mask path: 3*8*36 = 864 blocks cover 165888 words ----
    const int blk = ((bz - 4) * 8 + blockIdx.y) * 36 + blockIdx.x;
    const int w = blk * 256 + t;
    int c = 0;
    if (w < MWORDS) {
      const float4* p = (const float4*)(dist + (size_t)w * 32);
      uint32_t bits = 0;
#pragma unroll
      for (int q = 0; q < 8; ++q) {
        float4 v = p[q];
        bits |= (v.x < THR ? 1u : 0u) << (q * 4);
        bits |= (v.y < THR ? 1u : 0u) << (q * 4 + 1);
        bits |= (v.z < THR ? 1u : 0u) << (q * 4 + 2);
        bits |= (v.w < THR ? 1u : 0u) << (q * 4 + 3);
      }
      maskw[w] = bits;
      c = __popc(bits);
    }
#pragma unroll
    for (int off = 32; off; off >>= 1) c += __shfl_down(c, off, 64);
    __shared__ int mred[4];
    if ((t & 63) == 0) mred[t >> 6] = c;
    __syncthreads();
    if (t == 0)
      c_part[blk] = (unsigned int)(mred[0] + mred[1] + mred[2] + mred[3]);
    return;
  }

  // ---- pack path: block = (tensor, batch, 64-n tile). Thread t owns 4 n's
  // ((t&15)*4+j) and one 16-channel k-chunk (cb=t>>4); 16 strided float4 loads
  // land its data k-contiguously in registers. Norms via small LDS reduce;
  // fp16 results staged through an LDS transpose tile so global stores are
  // 256-B contiguous runs (16 lanes x 16 B, same row).
  const int b = blockIdx.y;
  const int n0 = blockIdx.x * 64;  // 36*64 = 2304
  const float* src; half_t* dst; int kh;
  switch (bz) {
    case 0:  src = y;  dst = At; kh = 0;    break;
    case 1:  src = z;  dst = At; kh = 2048; break;
    case 2:  src = zp; dst = Bt; kh = 0;    break;
    default: src = yp; dst = Bt; kh = 2048; break;
  }
  const int kbase = kh + b * 256;
  const int col4 = (t & 15) * 4;   // n offset within tile
  const int cb = t >> 4;           // 16-channel k-chunk

  const float* base = src + (size_t)(b * CH + cb * 16) * N + n0 + col4;
  float4 v[16];
#pragma unroll
  for (int i = 0; i < 16; ++i) v[i] = *(const float4*)(base + (size_t)i * N);

  float ss[4] = {0.f, 0.f, 0.f, 0.f};
#pragma unroll
  for (int i = 0; i < 16; ++i) {
    ss[0] = fmaf(v[i].x, v[i].x, ss[0]);
    ss[1] = fmaf(v[i].y, v[i].y, ss[1]);
    ss[2] = fmaf(v[i].z, v[i].z, ss[2]);
    ss[3] = fmaf(v[i].w, v[i].w, ss[3]);
  }
  __shared__ float partial[16][65];
  __shared__ float sc[64];
  __shared__ half_t tile[64 * LROW];  // transpose staging, odd word row stride
#pragma unroll
  for (int j = 0; j < 4; ++j) partial[cb][col4 + j] = ss[j];
  __syncthreads();
  if (t < 64) {
    float s = 0.f;
#pragma unroll
    for (int k = 0; k < 16; ++k) s += partial[k][t];
    sc[t] = 1.0f / fmaxf(sqrtf(s), EPS);
  }
  __syncthreads();

  // normalize -> fp16 -> LDS transpose tile
#pragma unroll
  for (int j = 0; j < 4; ++j) {
    const float scj = sc[col4 + j];
    union { half_t h[16]; f16x8 v2[2]; } u;
#pragma unroll
    for (int i = 0; i < 16; ++i)
      u.h[i] = (half_t)(((const float*)&v[i])[j] * scj);
    f16x8* q = (f16x8*)(tile + (col4 + j) * LROW + cb * 16);
    q[0] = u.v2[0];
    q[1] = u.v2[1];
  }
  __syncthreads();

  // write-out: thread (r = t>>4, c = t&15); 4 row-passes x 2 instr;
  // each instruction: 16 lanes x 16 B contiguous in one row (256-B runs).
  {
    const int r = t >> 4, c = t & 15;
#pragma unroll
    for (int p = 0; p < 4; ++p) {
      const int row = p * 16 + r;
      half_t* gout = dst + (size_t)(n0 + row) * KTOT + kbase;
      const half_t* lrow = tile + row * LROW;
#pragma unroll
      for (int inst = 0; inst < 2; ++inst) {
        const int off = c * 8 + inst * 128;
        *(f16x8*)(gout + off) = *(const f16x8*)(lrow + off);
      }
    }
  }
}

// ---------------- 2. GEMM s_part[bid] = sum_mask (At * Bt^T) tile ----------------
// 256x256 tile, 8 waves (2 n-groups x 4 m-groups, 128x64 per wave), BK=32,
// FOUR LDS buffers (128 KB) -> depth-3 staging pipeline with counted
// s_waitcnt vmcnt(8) per tile (T3+T4): never drain vmcnt to 0 in the loop,
// loads issued 3 tiles (~6 phases) before their wait.  One raw s_barrier per
// tile; setprio(1) around the MFMA cluster (T5).
// Grid: 81 output tiles x K-split 3 (43/43/42 BK-steps) = 243 blocks at
// 1 block/CU -> single dispatch round, no tail quantization.
// LDS swizzle (64-B rows, 4 chunks of 16 B): phys chunk = logical ^ ((row>>1)&3).
// Write side is linear (global_load_lds), source address pre-swizzled; read
// side applies the same XOR -> max 2-way bank aliasing (free, m136).
__global__ __launch_bounds__(512, 2) void gemm_kernel(
    const half_t* __restrict__ At, const half_t* __restrict__ Bt,
    const uint32_t* __restrict__ maskw, float* __restrict__ s_part) {
  __shared__ __align__(16) half_t As[4 * 8192];  // 4 bufs x 256 rows x 32 halfs
  __shared__ __align__(16) half_t Bs[4 * 8192];
  __shared__ float red[8];

  const int t = threadIdx.x;
  const int lane = t & 63;
  const int w8 = t >> 6;

  // bijective XCD swizzle (m204; 243 = 8*30 + 3): same-panel blocks same XCD
  const int orig = blockIdx.x;
  const int xcd = orig & 7;
  const int wid = (xcd < 3 ? xcd * 31 : 93 + (xcd - 3) * 30) + (orig >> 3);
  const int zt = wid / 81;          // K-slice
  const int t81 = wid % 81;
  const int n0 = (t81 / 9) * 256;   // At (n) tile base
  const int m0 = (t81 % 9) * 256;   // Bt (m) tile base
  const int k0 = zt * 1376;         // 43 steps * 32
  const int NT = 43 - (zt == 2);    // 43,43,42 -> 128 BK=32 steps total

  // staging: one block-wide global_load_lds = 512 lanes x 16 B = 128 rows x 64 B.
  // thread -> row t>>2, phys slot t&3; fetch global chunk (t&3)^((row>>1)&3).
  const int srow = t >> 2;
  const int schunk = ((t & 3) ^ ((srow >> 1) & 3)) * 8;  // halfs
  const half_t* gA = At + (size_t)(n0 + srow) * KTOT + k0 + schunk;
  const half_t* gB = Bt + (size_t)(m0 + srow) * KTOT + k0 + schunk;

  auto stage = [&](int j) {  // stage K-tile j into buffer j&3 (4 loads)
    const int buf = j & 3;
    const half_t* ga = gA + j * 32;
    const half_t* gb = gB + j * 32;
    half_t* la = As + buf * 8192 + w8 * 512;  // wave-uniform LDS bases
    half_t* lb = Bs + buf * 8192 + w8 * 512;
    __builtin_amdgcn_global_load_lds((const GLOBAL_AS void*)ga, (LDS_AS void*)la, 16, 0, 0);
    __builtin_amdgcn_global_load_lds((const GLOBAL_AS void*)(ga + (size_t)128 * KTOT),
                                     (LDS_AS void*)(la + 128 * 32), 16, 0, 0);
    __builtin_amdgcn_global_load_lds((const GLOBAL_AS void*)gb, (LDS_AS void*)lb, 16, 0, 0);
    __builtin_amdgcn_global_load_lds((const GLOBAL_AS void*)(gb + (size_t)128 * KTOT),
                                     (LDS_AS void*)(lb + 128 * 32), 16, 0, 0);
  };

  // fragment addressing: wave (wA,wB) owns n in [wA*128,+128), m in [wB*64,+64).
  const int fr = lane & 15;   // row-within-frag
  const int clog = lane >> 4; // logical k-chunk (16x16x32 A/B frag layout)
  const int wA = w8 >> 2;
  const int wB = w8 & 3;
  const int ksw = (clog ^ ((fr >> 1) & 3)) * 8;  // swizzled k offset (halfs)
  const int aoff = (wA * 128 + fr) * 32 + ksw;   // +i*512 per frag (imm-foldable)
  const int boff = (wB * 64 + fr) * 32 + ksw;

  f32x4 acc[8][4] = {};

// per-tile body: wait own staging (counted), barrier for cross-wave LDS
// visibility AND to retire buffer (kt-1)'s readers before (kt+3) overwrites it
// (bufs {kt,kt+1,kt+2,kt+3} are the 4 distinct buffers).  Memory-clobber asm
// pins LDS reads/writes inside their tile (rule: loads can't cross clobbers).
#define GEMM_TILE(KT, VMSTR, DO_STAGE)                                         \
  {                                                                            \
    asm volatile("s_waitcnt " VMSTR ::: "memory");                             \
    __builtin_amdgcn_s_barrier();                                              \
    asm volatile("" ::: "memory");                                             \
    if (DO_STAGE) stage((KT) + 3);                                             \
    const half_t* Ab = As + ((KT) & 3) * 8192;                                 \
    const half_t* Bb = Bs + ((KT) & 3) * 8192;                                 \
    f16x8 af[8], bf[4];                                                        \
    _Pragma("unroll") for (int j = 0; j < 4; ++j)                              \
        bf[j] = *(const f16x8*)(Bb + boff + j * 512);                          \
    _Pragma("unroll") for (int i = 0; i < 8; ++i)                              \
        af[i] = *(const f16x8*)(Ab + aoff + i * 512);                          \
    __builtin_amdgcn_s_setprio(1);                                             \
    _Pragma("unroll") for (int i = 0; i < 8; ++i)                              \
      _Pragma("unroll") for (int j = 0; j < 4; ++j)                            \
        acc[i][j] =                                                            \
            __builtin_amdgcn_mfma_f32_16x16x32_f16(af[i], bf[j], acc[i][j], 0, 0, 0); \
    __builtin_amdgcn_s_setprio(0);                                             \
  }

  stage(0); stage(1); stage(2);  // prologue: 12 loads in flight

  int kt = 0;
  for (; kt < NT - 3; ++kt) GEMM_TILE(kt, "vmcnt(8)", true);  // steady state
  GEMM_TILE(kt, "vmcnt(8)", false); ++kt;  // NT-3: {NT-2,NT-1} in flight
  GEMM_TILE(kt, "vmcnt(4)", false); ++kt;  // NT-2: {NT-1} in flight
  GEMM_TILE(kt, "vmcnt(0)", false);        // NT-1: final drain
#undef GEMM_TILE

  // masked-sum epilogue; C/D: col = lane&15 (m, 2nd operand), row = clog*4+reg (n).
  // wave m-span = 64 bits -> one aligned uint2 of mask words per n-row.
  float local = 0.f;
  const int mw0 = (m0 + wB * 64) >> 5;  // even -> uint2-aligned
#pragma unroll
  for (int i = 0; i < 8; ++i) {
    const int ng = n0 + wA * 128 + i * 16 + clog * 4;
#pragma unroll
    for (int r = 0; r < 4; ++r) {
      const uint2 wv = *(const uint2*)(maskw + (size_t)(ng + r) * MW + mw0);
#pragma unroll
      for (int j = 0; j < 4; ++j) {
        const uint32_t ww = (j & 2) ? wv.y : wv.x;
        if ((ww >> (fr + ((j & 1) << 4))) & 1u) local += acc[i][j][r];
      }
    }
  }
#pragma unroll
  for (int off = 32; off; off >>= 1) local += __shfl_down(local, off, 64);
  if (lane == 0) red[w8] = local;
  __syncthreads();
  if (t == 0) {
    float s = 0.f;
#pragma unroll
    for (int k = 0; k < 8; ++k) s += red[k];
    s_part[orig] = s;
  }
}

// ------- 3. finalize: reduce 243 s-partials + 864 count-partials -------
__global__ void finalize_kernel(const float* __restrict__ s_part,
                                const unsigned int* __restrict__ c_part,
                                float* __restrict__ out) {
  const int t = threadIdx.x;
  float local = 0.f;
  for (int i = t; i < NBLK; i += 256) local += s_part[i];
  unsigned int clocal = 0;
  for (int i = t; i < 864; i += 256) clocal += c_part[i];
#pragma unroll
  for (int off = 32; off; off >>= 1) {
    local += __shfl_down(local, off, 64);
    clocal += __shfl_down(clocal, off, 64);
  }
  __shared__ float red[4];
  __shared__ unsigned int credu[4];
  if ((t & 63) == 0) { red[t >> 6] = local; credu[t >> 6] = clocal; }
  __syncthreads();
  if (t == 0) {
    const float s = red[0] + red[1] + red[2] + red[3];
    const float cnt = (float)(credu[0] + credu[1] + credu[2] + credu[3]);
    out[0] = -s / (cnt * (float)BATCH);
  }
}

extern "C" void kernel_launch(void* const* d_in, const int* in_sizes, int n_in,
                              void* d_out, int out_size, void* d_ws, size_t ws_size,
                              hipStream_t stream) {
  const float* y    = (const float*)d_in[0];
  const float* yp   = (const float*)d_in[1];
  const float* z    = (const float*)d_in[2];
  const float* zp   = (const float*)d_in[3];
  const float* dist = (const float*)d_in[4];
  float* out = (float*)d_out;

  char* ws = (char*)d_ws;
  float* s_part = (float*)ws;
  unsigned int* c_part = (unsigned int*)(ws + 8192);
  half_t* At = (half_t*)(ws + 16384);
  half_t* Bt = (half_t*)(ws + 16384 + 18874368);
  uint32_t* maskw = (uint32_t*)(ws + 16384 + 2 * 18874368);

  prep_kernel<<<dim3(36, 8, 7), 256, 0, stream>>>(y, yp, z, zp, dist, At, Bt, maskw, c_part);
  gemm_kernel<<<dim3(NBLK), 512, 0, stream>>>(At, Bt, maskw, s_part);
  finalize_kernel<<<1, 256, 0, stream>>>(s_part, c_part, out);
}

// Round 3
// 178.477 us; speedup vs baseline: 1.0229x; 1.0229x over previous
//
#include <hip/hip_runtime.h>
#include <stdint.h>

#define GLOBAL_AS __attribute__((address_space(1)))
#define LDS_AS __attribute__((address_space(3)))

typedef _Float16 half_t;
typedef _Float16 f16x8 __attribute__((ext_vector_type(8)));
typedef float f32x4 __attribute__((ext_vector_type(4)));

static constexpr int BATCH = 8;
static constexpr int CH = 256;
static constexpr int N = 2304;     // 48*48
static constexpr int KTOT = 4096;  // 2 * BATCH * CH (G1 and G2 fused along K)
static constexpr int MW = 72;      // mask words per row (2304/32)
static constexpr int MWORDS = 165888;  // 2304*72
static constexpr int LROW = 258;   // LDS transpose row stride in halfs (odd word count)
static constexpr float EPS = 1e-8f;
static constexpr float THR = 31.5f;
static constexpr int NBLK = 243;   // 81 output tiles x 3 K-slices (single round, 1 blk/CU)

// ws layout (nothing needs pre-zeroing; every slot written unconditionally):
//   s_part  = ws         : float [243]  per-gemm-block masked-sum partials
//   c_part  = ws + 8192  : uint  [864]  per-mask-block popcount partials
//   At = ws + 16384            : half [2304][4096] rows=n, k-contig ([yhat; zhat])
//   Bt = At + 18874368 B       : half [2304][4096] rows=m, k-contig ([zphat; yphat])
//   maskw = Bt + 18874368 B    : uint32 [2304][72] bitmask of (dist < THR)
//
// NOTE (R3): identical to the R2 submission — that bench died to a container
// failure (no counters, no compile error; infra push times were already
// pathological in R1).  Kernel re-audited for hang risks (barrier divergence,
// waitcnt deadlock, ring-buffer races): none found.  Re-running to get the
// measurement for the fragment-pipelining theory.

// ------------- 1. prep: fused norm+pack (z<4) and mask build (z>=4) -------------
__global__ __launch_bounds__(256) void prep_kernel(
    const float* __restrict__ y, const float* __restrict__ yp,
    const float* __restrict__ z, const float* __restrict__ zp,
    const float* __restrict__ dist,
    half_t* __restrict__ At, half_t* __restrict__ Bt,
    uint32_t* __restrict__ maskw, unsigned int* __restrict__ c_part) {
  const int t = threadIdx.x;
  const int bz = blockIdx.z;

  if (bz >= 4) {
    // ---- mask path: 3*8*36 = 864 blocks cover 165888 words ----
    const int blk = ((bz - 4) * 8 + blockIdx.y) * 36 + blockIdx.x;
    const int w = blk * 256 + t;
    int c = 0;
    if (w < MWORDS) {
      const float4* p = (const float4*)(dist + (size_t)w * 32);
      uint32_t bits = 0;
#pragma unroll
      for (int q = 0; q < 8; ++q) {
        float4 v = p[q];
        bits |= (v.x < THR ? 1u : 0u) << (q * 4);
        bits |= (v.y < THR ? 1u : 0u) << (q * 4 + 1);
        bits |= (v.z < THR ? 1u : 0u) << (q * 4 + 2);
        bits |= (v.w < THR ? 1u : 0u) << (q * 4 + 3);
      }
      maskw[w] = bits;
      c = __popc(bits);
    }
#pragma unroll
    for (int off = 32; off; off >>= 1) c += __shfl_down(c, off, 64);
    __shared__ int mred[4];
    if ((t & 63) == 0) mred[t >> 6] = c;
    __syncthreads();
    if (t == 0)
      c_part[blk] = (unsigned int)(mred[0] + mred[1] + mred[2] + mred[3]);
    return;
  }

  // ---- pack path: block = (tensor, batch, 64-n tile). Thread t owns 4 n's
  // ((t&15)*4+j) and one 16-channel k-chunk (cb=t>>4); 16 strided float4 loads
  // land its data k-contiguously in registers. Norms via small LDS reduce;
  // fp16 results staged through an LDS transpose tile so global stores are
  // 256-B contiguous runs (16 lanes x 16 B, same row).
  const int b = blockIdx.y;
  const int n0 = blockIdx.x * 64;  // 36*64 = 2304
  const float* src; half_t* dst; int kh;
  switch (bz) {
    case 0:  src = y;  dst = At; kh = 0;    break;
    case 1:  src = z;  dst = At; kh = 2048; break;
    case 2:  src = zp; dst = Bt; kh = 0;    break;
    default: src = yp; dst = Bt; kh = 2048; break;
  }
  const int kbase = kh + b * 256;
  const int col4 = (t & 15) * 4;   // n offset within tile
  const int cb = t >> 4;           // 16-channel k-chunk

  const float* base = src + (size_t)(b * CH + cb * 16) * N + n0 + col4;
  float4 v[16];
#pragma unroll
  for (int i = 0; i < 16; ++i) v[i] = *(const float4*)(base + (size_t)i * N);

  float ss[4] = {0.f, 0.f, 0.f, 0.f};
#pragma unroll
  for (int i = 0; i < 16; ++i) {
    ss[0] = fmaf(v[i].x, v[i].x, ss[0]);
    ss[1] = fmaf(v[i].y, v[i].y, ss[1]);
    ss[2] = fmaf(v[i].z, v[i].z, ss[2]);
    ss[3] = fmaf(v[i].w, v[i].w, ss[3]);
  }
  __shared__ float partial[16][65];
  __shared__ float sc[64];
  __shared__ half_t tile[64 * LROW];  // transpose staging, odd word row stride
#pragma unroll
  for (int j = 0; j < 4; ++j) partial[cb][col4 + j] = ss[j];
  __syncthreads();
  if (t < 64) {
    float s = 0.f;
#pragma unroll
    for (int k = 0; k < 16; ++k) s += partial[k][t];
    sc[t] = 1.0f / fmaxf(sqrtf(s), EPS);
  }
  __syncthreads();

  // normalize -> fp16 -> LDS transpose tile
#pragma unroll
  for (int j = 0; j < 4; ++j) {
    const float scj = sc[col4 + j];
    union { half_t h[16]; f16x8 v2[2]; } u;
#pragma unroll
    for (int i = 0; i < 16; ++i)
      u.h[i] = (half_t)(((const float*)&v[i])[j] * scj);
    f16x8* q = (f16x8*)(tile + (col4 + j) * LROW + cb * 16);
    q[0] = u.v2[0];
    q[1] = u.v2[1];
  }
  __syncthreads();

  // write-out: thread (r = t>>4, c = t&15); 4 row-passes x 2 instr;
  // each instruction: 16 lanes x 16 B contiguous in one row (256-B runs).
  {
    const int r = t >> 4, c = t & 15;
#pragma unroll
    for (int p = 0; p < 4; ++p) {
      const int row = p * 16 + r;
      half_t* gout = dst + (size_t)(n0 + row) * KTOT + kbase;
      const half_t* lrow = tile + row * LROW;
#pragma unroll
      for (int inst = 0; inst < 2; ++inst) {
        const int off = c * 8 + inst * 128;
        *(f16x8*)(gout + off) = *(const f16x8*)(lrow + off);
      }
    }
  }
}

// ---------------- 2. GEMM s_part[bid] = sum_mask (At * Bt^T) tile ----------------
// 256x256 tile, 8 waves (2 n-groups x 4 m-groups, 128x64 per wave), BK=32,
// ring-4 LDS (128 KB) + counted vmcnt (as R1) PLUS register-level fragment
// pipelining: tile kt+1's af/bf frags are ds_read DURING tile kt's MFMA
// clusters (two 16-MFMA half-clusters per tile), so the ~1150-cy/CU LDS read
// window hides under the 1242-cy/CU matrix window instead of serializing
// after it (R1 post-mortem: 3180 cy/tile = reads + MFMA with ZERO overlap).
// Named register sets (af0/bf0, af1/bf1) alternate per tile -> static indexing.
// vmcnt(4) at body top = tile kt+1 fully staged (issued 2 bodies ago, no
// stall) so next-tile reads inside body kt are safe; barrier propagates
// cross-wave. Ring audit: body kt reads bufs {kt,kt+1}&3; stage writes
// (kt+3)&3=(kt-1)&3 whose readers lgkm-retired before this body's barrier.
// K-split 44/42/42 steps (even per block) -> clean 2-unroll + 4 peeled bodies.
__global__ __launch_bounds__(512, 2) void gemm_kernel(
    const half_t* __restrict__ At, const half_t* __restrict__ Bt,
    const uint32_t* __restrict__ maskw, float* __restrict__ s_part) {
  __shared__ __align__(16) half_t As[4 * 8192];  // 4 bufs x 256 rows x 32 halfs
  __shared__ __align__(16) half_t Bs[4 * 8192];
  __shared__ float red[8];

  const int t = threadIdx.x;
  const int lane = t & 63;
  const int w8 = t >> 6;

  // bijective XCD swizzle (m204; 243 = 8*30 + 3): same-panel blocks same XCD
  const int orig = blockIdx.x;
  const int xcd = orig & 7;
  const int wid = (xcd < 3 ? xcd * 31 : 93 + (xcd - 3) * 30) + (orig >> 3);
  const int zt = wid / 81;          // K-slice
  const int t81 = wid % 81;
  const int n0 = (t81 / 9) * 256;   // At (n) tile base
  const int m0 = (t81 % 9) * 256;   // Bt (m) tile base
  const int k0 = zt ? (1408 + (zt - 1) * 1344) : 0;  // 44/42/42 BK=32 steps
  const int NT = zt ? 42 : 44;

  // staging: one block-wide global_load_lds = 512 lanes x 16 B = 128 rows x 64 B.
  // thread -> row t>>2, phys slot t&3; fetch global chunk (t&3)^((row>>1)&3).
  const int srow = t >> 2;
  const int schunk = ((t & 3) ^ ((srow >> 1) & 3)) * 8;  // halfs
  const half_t* gA = At + (size_t)(n0 + srow) * KTOT + k0 + schunk;
  const half_t* gB = Bt + (size_t)(m0 + srow) * KTOT + k0 + schunk;

  auto stage = [&](int j) {  // stage K-tile j into buffer j&3 (4 loads)
    const int buf = j & 3;
    const half_t* ga = gA + j * 32;
    const half_t* gb = gB + j * 32;
    half_t* la = As + buf * 8192 + w8 * 512;  // wave-uniform LDS bases
    half_t* lb = Bs + buf * 8192 + w8 * 512;
    __builtin_amdgcn_global_load_lds((const GLOBAL_AS void*)ga, (LDS_AS void*)la, 16, 0, 0);
    __builtin_amdgcn_global_load_lds((const GLOBAL_AS void*)(ga + (size_t)128 * KTOT),
                                     (LDS_AS void*)(la + 128 * 32), 16, 0, 0);
    __builtin_amdgcn_global_load_lds((const GLOBAL_AS void*)gb, (LDS_AS void*)lb, 16, 0, 0);
    __builtin_amdgcn_global_load_lds((const GLOBAL_AS void*)(gb + (size_t)128 * KTOT),
                                     (LDS_AS void*)(lb + 128 * 32), 16, 0, 0);
  };

  // fragment addressing: wave (wA,wB) owns n in [wA*128,+128), m in [wB*64,+64).
  const int fr = lane & 15;   // row-within-frag
  const int clog = lane >> 4; // logical k-chunk (16x16x32 A/B frag layout)
  const int wA = w8 >> 2;
  const int wB = w8 & 3;
  const int ksw = (clog ^ ((fr >> 1) & 3)) * 8;  // swizzled k offset (halfs)
  const int aoff = (wA * 128 + fr) * 32 + ksw;   // +i*512 per frag (imm-foldable)
  const int boff = (wB * 64 + fr) * 32 + ksw;

  f32x4 acc[8][4] = {};

#define READ_A(dst, BUF, IBASE)                                                \
  _Pragma("unroll") for (int i = 0; i < 4; ++i)                                \
      dst[i] = *(const f16x8*)(As + (BUF) * 8192 + aoff + ((IBASE) + i) * 512);
#define READ_B(dst, BUF)                                                       \
  _Pragma("unroll") for (int j = 0; j < 4; ++j)                                \
      dst[j] = *(const f16x8*)(Bs + (BUF) * 8192 + boff + j * 512);

// body kt: CA/CB = current tile's frags (af i=0..3 / bf, preloaded last body);
// NA/NB = next tile's frag set, read mid-body between the two MFMA clusters.
// afh = current tile's af i=4..7, read at body start, used by cluster 2.
#define BODY(KT, CA, CB, NA, NB, VMSTR, DO_STAGE, DO_NEXT)                     \
  {                                                                            \
    asm volatile("s_waitcnt " VMSTR ::: "memory");                             \
    __builtin_amdgcn_s_barrier();                                              \
    asm volatile("" ::: "memory");                                             \
    if (DO_STAGE) stage((KT) + 3);                                             \
    f16x8 afh[4];                                                              \
    READ_A(afh, (KT) & 3, 4);                                                  \
    __builtin_amdgcn_s_setprio(1);                                             \
    _Pragma("unroll") for (int i = 0; i < 4; ++i)                              \
      _Pragma("unroll") for (int j = 0; j < 4; ++j)                            \
        acc[i][j] =                                                            \
            __builtin_amdgcn_mfma_f32_16x16x32_f16(CA[i], CB[j], acc[i][j], 0, 0, 0); \
    __builtin_amdgcn_s_setprio(0);                                             \
    if (DO_NEXT) {                                                             \
      READ_B(NB, ((KT) + 1) & 3);                                              \
      READ_A(NA, ((KT) + 1) & 3, 0);                                           \
    }                                                                          \
    __builtin_amdgcn_s_setprio(1);                                             \
    _Pragma("unroll") for (int i = 0; i < 4; ++i)                              \
      _Pragma("unroll") for (int j = 0; j < 4; ++j)                            \
        acc[4 + i][j] =                                                        \
            __builtin_amdgcn_mfma_f32_16x16x32_f16(afh[i], CB[j], acc[4 + i][j], 0, 0, 0); \
    __builtin_amdgcn_s_setprio(0);                                             \
  }

  // prologue: 12 loads in flight; wait tile 0 only (vmcnt(8)), preload set 0
  stage(0); stage(1); stage(2);
  asm volatile("s_waitcnt vmcnt(8)" ::: "memory");
  __builtin_amdgcn_s_barrier();
  asm volatile("" ::: "memory");
  f16x8 af0[4], bf0[4], af1[4], bf1[4];
  READ_B(bf0, 0);
  READ_A(af0, 0, 0);

  int kt = 0;
  for (; kt < NT - 4; kt += 2) {  // NT even; NT-4 even
    BODY(kt,     af0, bf0, af1, bf1, "vmcnt(4)", true, true);
    BODY(kt + 1, af1, bf1, af0, bf0, "vmcnt(4)", true, true);
  }
  BODY(NT - 4, af0, bf0, af1, bf1, "vmcnt(4)", true,  true);
  BODY(NT - 3, af1, bf1, af0, bf0, "vmcnt(4)", false, true);
  BODY(NT - 2, af0, bf0, af1, bf1, "vmcnt(0)", false, true);
  BODY(NT - 1, af1, bf1, af0, bf0, "vmcnt(0)", false, false);
#undef BODY
#undef READ_A
#undef READ_B

  // masked-sum epilogue; C/D: col = lane&15 (m, 2nd operand), row = clog*4+reg (n).
  // wave m-span = 64 bits -> one aligned uint2 of mask words per n-row.
  float local = 0.f;
  const int mw0 = (m0 + wB * 64) >> 5;  // even -> uint2-aligned
#pragma unroll
  for (int i = 0; i < 8; ++i) {
    const int ng = n0 + wA * 128 + i * 16 + clog * 4;
#pragma unroll
    for (int r = 0; r < 4; ++r) {
      const uint2 wv = *(const uint2*)(maskw + (size_t)(ng + r) * MW + mw0);
#pragma unroll
      for (int j = 0; j < 4; ++j) {
        const uint32_t ww = (j & 2) ? wv.y : wv.x;
        if ((ww >> (fr + ((j & 1) << 4))) & 1u) local += acc[i][j][r];
      }
    }
  }
#pragma unroll
  for (int off = 32; off; off >>= 1) local += __shfl_down(local, off, 64);
  if (lane == 0) red[w8] = local;
  __syncthreads();
  if (t == 0) {
    float s = 0.f;
#pragma unroll
    for (int k = 0; k < 8; ++k) s += red[k];
    s_part[orig] = s;
  }
}

// ------- 3. finalize: reduce 243 s-partials + 864 count-partials -------
__global__ void finalize_kernel(const float* __restrict__ s_part,
                                const unsigned int* __restrict__ c_part,
                                float* __restrict__ out) {
  const int t = threadIdx.x;
  float local = 0.f;
  for (int i = t; i < NBLK; i += 256) local += s_part[i];
  unsigned int clocal = 0;
  for (int i = t; i < 864; i += 256) clocal += c_part[i];
#pragma unroll
  for (int off = 32; off; off >>= 1) {
    local += __shfl_down(local, off, 64);
    clocal += __shfl_down(clocal, off, 64);
  }
  __shared__ float red[4];
  __shared__ unsigned int credu[4];
  if ((t & 63) == 0) { red[t >> 6] = local; credu[t >> 6] = clocal; }
  __syncthreads();
  if (t == 0) {
    const float s = red[0] + red[1] + red[2] + red[3];
    const float cnt = (float)(credu[0] + credu[1] + credu[2] + credu[3]);
    out[0] = -s / (cnt * (float)BATCH);
  }
}

extern "C" void kernel_launch(void* const* d_in, const int* in_sizes, int n_in,
                              void* d_out, int out_size, void* d_ws, size_t ws_size,
                              hipStream_t stream) {
  const float* y    = (const float*)d_in[0];
  const float* yp   = (const float*)d_in[1];
  const float* z    = (const float*)d_in[2];
  const float* zp   = (const float*)d_in[3];
  const float* dist = (const float*)d_in[4];
  float* out = (float*)d_out;

  char* ws = (char*)d_ws;
  float* s_part = (float*)ws;
  unsigned int* c_part = (unsigned int*)(ws + 8192);
  half_t* At = (half_t*)(ws + 16384);
  half_t* Bt = (half_t*)(ws + 16384 + 18874368);
  uint32_t* maskw = (uint32_t*)(ws + 16384 + 2 * 18874368);

  prep_kernel<<<dim3(36, 8, 7), 256, 0, stream>>>(y, yp, z, zp, dist, At, Bt, maskw, c_part);
  gemm_kernel<<<dim3(NBLK), 512, 0, stream>>>(At, Bt, maskw, s_part);
  finalize_kernel<<<1, 256, 0, stream>>>(s_part, c_part, out);
}

// Round 4
// 175.923 us; speedup vs baseline: 1.0377x; 1.0145x over previous
//
#include <hip/hip_runtime.h>
#include <stdint.h>

#define GLOBAL_AS __attribute__((address_space(1)))
#define LDS_AS __attribute__((address_space(3)))

typedef _Float16 half_t;
typedef _Float16 f16x8 __attribute__((ext_vector_type(8)));
typedef float f32x4 __attribute__((ext_vector_type(4)));

static constexpr int BATCH = 8;
static constexpr int CH = 256;
static constexpr int N = 2304;     // 48*48
static constexpr int KTOT = 4096;  // 2 * BATCH * CH (G1 and G2 fused along K)
static constexpr int MW = 72;      // mask words per row (2304/32)
static constexpr int MWORDS = 165888;  // 2304*72
static constexpr int LROW = 258;   // LDS transpose row stride in halfs (odd word count)
static constexpr float EPS = 1e-8f;
static constexpr float THR = 31.5f;
static constexpr int NBLK = 243;   // 81 output tiles x 3 K-slices (single round, 1 blk/CU)

// ws layout (nothing needs pre-zeroing; every slot written unconditionally):
//   s_part  = ws         : float [243]  per-gemm-block masked-sum partials
//   c_part  = ws + 8192  : uint  [864]  per-mask-block popcount partials
//   At = ws + 16384            : half [2304][4096] rows=n, k-contig ([yhat; zhat])
//   Bt = At + 18874368 B       : half [2304][4096] rows=m, k-contig ([zphat; yphat])
//   maskw = Bt + 18874368 B    : uint32 [2304][72] bitmask of (dist < THR)

// ------------- 1. prep: fused norm+pack (z<4) and mask build (z>=4) -------------
__global__ __launch_bounds__(256) void prep_kernel(
    const float* __restrict__ y, const float* __restrict__ yp,
    const float* __restrict__ z, const float* __restrict__ zp,
    const float* __restrict__ dist,
    half_t* __restrict__ At, half_t* __restrict__ Bt,
    uint32_t* __restrict__ maskw, unsigned int* __restrict__ c_part) {
  const int t = threadIdx.x;
  const int bz = blockIdx.z;

  if (bz >= 4) {
    // ---- mask path: 3*8*36 = 864 blocks cover 165888 words ----
    const int blk = ((bz - 4) * 8 + blockIdx.y) * 36 + blockIdx.x;
    const int w = blk * 256 + t;
    int c = 0;
    if (w < MWORDS) {
      const float4* p = (const float4*)(dist + (size_t)w * 32);
      uint32_t bits = 0;
#pragma unroll
      for (int q = 0; q < 8; ++q) {
        float4 v = p[q];
        bits |= (v.x < THR ? 1u : 0u) << (q * 4);
        bits |= (v.y < THR ? 1u : 0u) << (q * 4 + 1);
        bits |= (v.z < THR ? 1u : 0u) << (q * 4 + 2);
        bits |= (v.w < THR ? 1u : 0u) << (q * 4 + 3);
      }
      maskw[w] = bits;
      c = __popc(bits);
    }
#pragma unroll
    for (int off = 32; off; off >>= 1) c += __shfl_down(c, off, 64);
    __shared__ int mred[4];
    if ((t & 63) == 0) mred[t >> 6] = c;
    __syncthreads();
    if (t == 0)
      c_part[blk] = (unsigned int)(mred[0] + mred[1] + mred[2] + mred[3]);
    return;
  }

  // ---- pack path: block = (tensor, batch, 64-n tile). Thread t owns 4 n's
  // ((t&15)*4+j) and one 16-channel k-chunk (cb=t>>4); 16 strided float4 loads
  // land its data k-contiguously in registers. Norms via small LDS reduce;
  // fp16 results staged through an LDS transpose tile so global stores are
  // 256-B contiguous runs (16 lanes x 16 B, same row).
  const int b = blockIdx.y;
  const int n0 = blockIdx.x * 64;  // 36*64 = 2304
  const float* src; half_t* dst; int kh;
  switch (bz) {
    case 0:  src = y;  dst = At; kh = 0;    break;
    case 1:  src = z;  dst = At; kh = 2048; break;
    case 2:  src = zp; dst = Bt; kh = 0;    break;
    default: src = yp; dst = Bt; kh = 2048; break;
  }
  const int kbase = kh + b * 256;
  const int col4 = (t & 15) * 4;   // n offset within tile
  const int cb = t >> 4;           // 16-channel k-chunk

  const float* base = src + (size_t)(b * CH + cb * 16) * N + n0 + col4;
  float4 v[16];
#pragma unroll
  for (int i = 0; i < 16; ++i) v[i] = *(const float4*)(base + (size_t)i * N);

  float ss[4] = {0.f, 0.f, 0.f, 0.f};
#pragma unroll
  for (int i = 0; i < 16; ++i) {
    ss[0] = fmaf(v[i].x, v[i].x, ss[0]);
    ss[1] = fmaf(v[i].y, v[i].y, ss[1]);
    ss[2] = fmaf(v[i].z, v[i].z, ss[2]);
    ss[3] = fmaf(v[i].w, v[i].w, ss[3]);
  }
  __shared__ float partial[16][65];
  __shared__ float sc[64];
  __shared__ half_t tile[64 * LROW];  // transpose staging, odd word row stride
#pragma unroll
  for (int j = 0; j < 4; ++j) partial[cb][col4 + j] = ss[j];
  __syncthreads();
  if (t < 64) {
    float s = 0.f;
#pragma unroll
    for (int k = 0; k < 16; ++k) s += partial[k][t];
    sc[t] = 1.0f / fmaxf(sqrtf(s), EPS);
  }
  __syncthreads();

  // normalize -> fp16 -> LDS transpose tile
#pragma unroll
  for (int j = 0; j < 4; ++j) {
    const float scj = sc[col4 + j];
    union { half_t h[16]; f16x8 v2[2]; } u;
#pragma unroll
    for (int i = 0; i < 16; ++i)
      u.h[i] = (half_t)(((const float*)&v[i])[j] * scj);
    f16x8* q = (f16x8*)(tile + (col4 + j) * LROW + cb * 16);
    q[0] = u.v2[0];
    q[1] = u.v2[1];
  }
  __syncthreads();

  // write-out: thread (r = t>>4, c = t&15); 4 row-passes x 2 instr;
  // each instruction: 16 lanes x 16 B contiguous in one row (256-B runs).
  {
    const int r = t >> 4, c = t & 15;
#pragma unroll
    for (int p = 0; p < 4; ++p) {
      const int row = p * 16 + r;
      half_t* gout = dst + (size_t)(n0 + row) * KTOT + kbase;
      const half_t* lrow = tile + row * LROW;
#pragma unroll
      for (int inst = 0; inst < 2; ++inst) {
        const int off = c * 8 + inst * 128;
        *(f16x8*)(gout + off) = *(const f16x8*)(lrow + off);
      }
    }
  }
}

// ---------------- 2. GEMM s_part[bid] = sum_mask (At * Bt^T) tile ----------------
// m201 8-phase template port (HW-verified 62% MfmaUtil on this exact geometry):
// 256x256 tile, 8 waves (2 A-groups x 4 B-groups, wave tile 128x64), BK=64,
// 2 LDS buffers (tile parity), 2 K-tiles per iteration = 8 phases of
// {ds-read frag subtile (8 or 4 x b128) ; stage 2 x 8KB global_load_lds ;
//  [vmcnt gate at P4/P8 only] ; s_barrier ; lgkmcnt(0) ; 16 MFMA ; s_barrier}.
// Phase = (qa half of wave's 128 A-rows, k half of BK=64): A-frags read fresh
// each phase (4 b128), B-frags read on k-half change (4 b128, carried one phase).
// Stage rotation (unit = 64 rows x 64 k = 8 KB, 1 global_load_lds block-wide):
//   P1: A1,A3(u)   P2: B0,B1(u)   P3: B2,B3(u)   P4: A0,A2(t2)+vmcnt(2)
//   P5: A1,A3(t2)  P6: B0,B1(t2)  P7: B2,B3(t2)  P8: A0,A2(t3)+vmcnt(2)
// (u=2j+1 buf1, t2=2j+2 buf0, t3=2j+3 buf1). Each unit's restage slot is
// strictly after its last reader's lgkmcnt(0)+barrier -> race-free; vmcnt(2)
// at P4/P8 retires the upcoming tile's 8 loads while leaving 4 in flight
// (never drains to 0 in the loop - T4). LDS swizzle: phys k-chunk =
// logical ^ (row&7); linear gload_lds dest + pre-swizzled source + swizzled
// ds_read (rule 21); frag b128 reads saturate all 8 bank groups (min 8 cy).
// K-split 22/22/20 BK=64 tiles per block (even -> clean 2-tile iterations).
__global__ __launch_bounds__(512, 2) void gemm_kernel(
    const half_t* __restrict__ At, const half_t* __restrict__ Bt,
    const uint32_t* __restrict__ maskw, float* __restrict__ s_part) {
  __shared__ __align__(16) half_t As[2 * 16384];  // 2 bufs x 256 rows x 64 halfs
  __shared__ __align__(16) half_t Bs[2 * 16384];
  __shared__ float red[8];

  const int t = threadIdx.x;
  const int lane = t & 63;
  const int w8 = t >> 6;

  // bijective XCD swizzle (m204; 243 = 8*30 + 3): same-panel blocks same XCD
  const int orig = blockIdx.x;
  const int xcd = orig & 7;
  const int wid = (xcd < 3 ? xcd * 31 : 93 + (xcd - 3) * 30) + (orig >> 3);
  const int zt = wid / 81;          // K-slice
  const int t81 = wid % 81;
  const int n0 = (t81 / 9) * 256;   // At (n) tile base
  const int m0 = (t81 % 9) * 256;   // Bt (m) tile base
  const int k0 = zt * 1408;         // 22/22/20 BK=64 tiles
  const int NI = (zt == 2) ? 10 : 11;  // iterations (2 tiles each)

  // staging: one global_load_lds = 512 threads x 16 B = 64 rows x 64 halfs.
  // thread -> row t>>3, phys chunk t&7; fetch global chunk (t&7)^(row&7).
  const int srow = t >> 3;
  const int schunk8 = ((t & 7) ^ (srow & 7)) * 8;  // halfs
  const half_t* gA = At + (size_t)(n0 + srow) * KTOT + k0 + schunk8;
  const half_t* gB = Bt + (size_t)(m0 + srow) * KTOT + k0 + schunk8;
  const int ldsw = w8 * 512;  // wave-uniform LDS base offset (halfs)

  auto SA = [&](int tl, int u, int buf) {  // stage A unit u (64 rows) of K-tile tl
    __builtin_amdgcn_global_load_lds(
        (const GLOBAL_AS void*)(gA + (size_t)(u * 64) * KTOT + tl * 64),
        (LDS_AS void*)(As + buf * 16384 + u * 4096 + ldsw), 16, 0, 0);
  };
  auto SB = [&](int tl, int u, int buf) {
    __builtin_amdgcn_global_load_lds(
        (const GLOBAL_AS void*)(gB + (size_t)(u * 64) * KTOT + tl * 64),
        (LDS_AS void*)(Bs + buf * 16384 + u * 4096 + ldsw), 16, 0, 0);
  };

  // fragment addressing: wave (wA,wB) owns n in [wA*128,+128), m in [wB*64,+64).
  const int fr = lane & 15;   // row-within-frag
  const int cl = lane >> 4;   // logical k-chunk within k-half
  const int e = lane & 7;     // = fr & 7 (row parity for swizzle)
  const int ksw0 = ((((cl ^ e) & 3)) | (e & 4)) * 8;  // phys chunk, k-half 0
  const int ksw1 = ksw0 ^ 32;                         // k-half 1 flips bit2
  const int wA = w8 >> 2;
  const int wB = w8 & 3;
  const int aoff = (wA * 128 + fr) * 64;  // + qa*4096 + pos*1024 + ksw
  const int boff = (wB * 64 + fr) * 64;   // + pos*1024 + ksw

  f32x4 acc[8][4] = {};
  f16x8 af[4], bf[4];

#define RD_A(BUF, QA, KSW)                                                     \
  _Pragma("unroll") for (int i = 0; i < 4; ++i)                                \
      af[i] = *(const f16x8*)(As + (BUF) * 16384 + aoff + (QA) * 4096 +        \
                              i * 1024 + (KSW));
#define RD_B(BUF, KSW)                                                         \
  _Pragma("unroll") for (int j = 0; j < 4; ++j)                                \
      bf[j] = *(const f16x8*)(Bs + (BUF) * 16384 + boff + j * 1024 + (KSW));
#define MM(QA)                                                                 \
  __builtin_amdgcn_s_setprio(1);                                               \
  _Pragma("unroll") for (int i = 0; i < 4; ++i)                                \
    _Pragma("unroll") for (int j = 0; j < 4; ++j)                              \
      acc[(QA) * 4 + i][j] = __builtin_amdgcn_mfma_f32_16x16x32_f16(           \
          af[i], bf[j], acc[(QA) * 4 + i][j], 0, 0, 0);                        \
  __builtin_amdgcn_s_setprio(0);
#define BARMID                                                                 \
  __builtin_amdgcn_s_barrier();                                                \
  asm volatile("s_waitcnt lgkmcnt(0)" ::: "memory");
#define BAREND __builtin_amdgcn_s_barrier();

// one iteration: tiles tt=2j (buf0) and u=2j+1 (buf1); stage u's remaining
// units (P1-P3), then t2=2j+2 (P4-P7) and t3=2j+3's A0,A2 (P8) when SN.
#define ITER(SN)                                                               \
  {                                                                            \
    const int u = 2 * j + 1, t2 = 2 * j + 2, t3 = 2 * j + 3;                   \
    /* P1: (qa0,k0) */                                                         \
    RD_A(0, 0, ksw0); RD_B(0, ksw0);                                           \
    SA(u, 1, 1); SA(u, 3, 1);                                                  \
    BARMID; MM(0); BAREND;                                                     \
    /* P2: (qa1,k0) */                                                         \
    RD_A(0, 1, ksw0);                                                          \
    SB(u, 0, 1); SB(u, 1, 1);                                                  \
    BARMID; MM(1); BAREND;                                                     \
    /* P3: (qa0,k1) */                                                         \
    RD_A(0, 0, ksw1); RD_B(0, ksw1);                                           \
    SB(u, 2, 1); SB(u, 3, 1);                                                  \
    BARMID; MM(0); BAREND;                                                     \
    /* P4: (qa1,k1) + gate tile u */                                           \
    RD_A(0, 1, ksw1);                                                          \
    if (SN) {                                                                  \
      SA(t2, 0, 0); SA(t2, 2, 0);                                              \
      asm volatile("s_waitcnt vmcnt(2)" ::: "memory");                         \
    } else {                                                                   \
      asm volatile("s_waitcnt vmcnt(0)" ::: "memory");                         \
    }                                                                          \
    BARMID; MM(1); BAREND;                                                     \
    /* P5: (qa0,k0) of u */                                                    \
    RD_A(1, 0, ksw0); RD_B(1, ksw0);                                           \
    if (SN) { SA(t2, 1, 0); SA(t2, 3, 0); }                                    \
    BARMID; MM(0); BAREND;                                                     \
    /* P6 */                                                                   \
    RD_A(1, 1, ksw0);                                                          \
    if (SN) { SB(t2, 0, 0); SB(t2, 1, 0); }                                    \
    BARMID; MM(1); BAREND;                                                     \
    /* P7 */                                                                   \
    RD_A(1, 0, ksw1); RD_B(1, ksw1);                                           \
    if (SN) { SB(t2, 2, 0); SB(t2, 3, 0); }                                    \
    BARMID; MM(0); BAREND;                                                     \
    /* P8 + gate tile t2 */                                                    \
    RD_A(1, 1, ksw1);                                                          \
    if (SN) {                                                                  \
      SA(t3, 0, 1); SA(t3, 2, 1);                                              \
      asm volatile("s_waitcnt vmcnt(2)" ::: "memory");                         \
    }                                                                          \
    BARMID; MM(1); BAREND;                                                     \
  }

  // prologue: tile0 fully (8 loads) + tile1 units A0,A2 (2 loads); gate tile0.
  SA(0, 0, 0); SA(0, 1, 0); SA(0, 2, 0); SA(0, 3, 0);
  SB(0, 0, 0); SB(0, 1, 0); SB(0, 2, 0); SB(0, 3, 0);
  SA(1, 0, 1); SA(1, 2, 1);
  asm volatile("s_waitcnt vmcnt(2)" ::: "memory");
  __builtin_amdgcn_s_barrier();

  int j = 0;
  for (; j < NI - 1; ++j) ITER(true);
  ITER(false);
#undef ITER
#undef RD_A
#undef RD_B
#undef MM
#undef BARMID
#undef BAREND

  // masked-sum epilogue; C/D: col = lane&15 (m, 2nd operand), row = cl*4+reg (n).
  // acc[a][j]: n rows n0 + wA*128 + a*16, m cols m0 + wB*64 + j*16.
  float local = 0.f;
  const int mw0 = (m0 + wB * 64) >> 5;  // even -> uint2-aligned
#pragma unroll
  for (int i = 0; i < 8; ++i) {
    const int ng = n0 + wA * 128 + i * 16 + cl * 4;
#pragma unroll
    for (int r = 0; r < 4; ++r) {
      const uint2 wv = *(const uint2*)(maskw + (size_t)(ng + r) * MW + mw0);
#pragma unroll
      for (int j2 = 0; j2 < 4; ++j2) {
        const uint32_t ww = (j2 & 2) ? wv.y : wv.x;
        if ((ww >> (fr + ((j2 & 1) << 4))) & 1u) local += acc[i][j2][r];
      }
    }
  }
#pragma unroll
  for (int off = 32; off; off >>= 1) local += __shfl_down(local, off, 64);
  if (lane == 0) red[w8] = local;
  __syncthreads();
  if (t == 0) {
    float s = 0.f;
#pragma unroll
    for (int k = 0; k < 8; ++k) s += red[k];
    s_part[orig] = s;
  }
}

// ------- 3. finalize: reduce 243 s-partials + 864 count-partials -------
__global__ void finalize_kernel(const float* __restrict__ s_part,
                                const unsigned int* __restrict__ c_part,
                                float* __restrict__ out) {
  const int t = threadIdx.x;
  float local = 0.f;
  for (int i = t; i < NBLK; i += 256) local += s_part[i];
  unsigned int clocal = 0;
  for (int i = t; i < 864; i += 256) clocal += c_part[i];
#pragma unroll
  for (int off = 32; off; off >>= 1) {
    local += __shfl_down(local, off, 64);
    clocal += __shfl_down(clocal, off, 64);
  }
  __shared__ float red[4];
  __shared__ unsigned int credu[4];
  if ((t & 63) == 0) { red[t >> 6] = local; credu[t >> 6] = clocal; }
  __syncthreads();
  if (t == 0) {
    const float s = red[0] + red[1] + red[2] + red[3];
    const float cnt = (float)(credu[0] + credu[1] + credu[2] + credu[3]);
    out[0] = -s / (cnt * (float)BATCH);
  }
}

extern "C" void kernel_launch(void* const* d_in, const int* in_sizes, int n_in,
                              void* d_out, int out_size, void* d_ws, size_t ws_size,
                              hipStream_t stream) {
  const float* y    = (const float*)d_in[0];
  const float* yp   = (const float*)d_in[1];
  const float* z    = (const float*)d_in[2];
  const float* zp   = (const float*)d_in[3];
  const float* dist = (const float*)d_in[4];
  float* out = (float*)d_out;

  char* ws = (char*)d_ws;
  float* s_part = (float*)ws;
  unsigned int* c_part = (unsigned int*)(ws + 8192);
  half_t* At = (half_t*)(ws + 16384);
  half_t* Bt = (half_t*)(ws + 16384 + 18874368);
  uint32_t* maskw = (uint32_t*)(ws + 16384 + 2 * 18874368);

  prep_kernel<<<dim3(36, 8, 7), 256, 0, stream>>>(y, yp, z, zp, dist, At, Bt, maskw, c_part);
  gemm_kernel<<<dim3(NBLK), 512, 0, stream>>>(At, Bt, maskw, s_part);
  finalize_kernel<<<1, 256, 0, stream>>>(s_part, c_part, out);
}